// Round 1
// baseline (249.391 us; speedup 1.0000x reference)
//
#include <hip/hip_runtime.h>
#include <math.h>

#define DIM 4096
// SCALE = 1/sqrt(4096) = 1/64 exactly
#define FF_SCALE 0.015625f

// In-register 16-point unnormalized Walsh-Hadamard transform.
// Stage order is irrelevant (stages commute), matches reference semantics.
__device__ __forceinline__ void fwht16(float v[16]) {
#pragma unroll
    for (int h = 1; h < 16; h <<= 1) {
#pragma unroll
        for (int i = 0; i < 16; ++i) {
            if ((i & h) == 0) {
                float a = v[i];
                float b = v[i + h];
                v[i] = a + b;
                v[i + h] = a - b;
            }
        }
    }
}

// LDS swizzle: p(i) = i ^ (((i>>8)&1)<<4)
// - keeps each aligned 16-float group contiguous (float4 LDS ops OK)
// - stride-16 and stride-256 access rounds drop from 4-way to 2-way bank
//   conflicts (2-way is free on CDNA4).
__device__ __forceinline__ int swz(int i) {
    return i ^ (((i >> 8) & 1) << 4);
}

__global__ __launch_bounds__(256) void fastfood_kernel(
    const float* __restrict__ x,
    const float* __restrict__ d1,
    const float* __restrict__ d2,
    const float* __restrict__ gauss_d,
    const int* __restrict__ perm,
    float* __restrict__ out)
{
    __shared__ float lds[DIM];
    const int t = threadIdx.x;
    const int row = blockIdx.x;
    const float* xrow = x + (size_t)row * DIM;
    float* orow = out + (size_t)row * DIM;

    float v[16];

    // ---- Round 1 (first FWHT): load x * d1, FWHT over digit c (h=1..8) ----
    {
        const float4* xv = (const float4*)(xrow + t * 16);
        const float4* dv = (const float4*)(d1 + t * 16);
#pragma unroll
        for (int q = 0; q < 4; ++q) {
            float4 aa = xv[q];
            float4 dd = dv[q];
            v[4 * q + 0] = aa.x * dd.x;
            v[4 * q + 1] = aa.y * dd.y;
            v[4 * q + 2] = aa.z * dd.z;
            v[4 * q + 3] = aa.w * dd.w;
        }
    }
    fwht16(v);
    {
        // group index t, swizzled: bit0 of group ^= (t>>4)&1
        int g = t ^ ((t >> 4) & 1);
        float4* l = (float4*)(lds + g * 16);
#pragma unroll
        for (int q = 0; q < 4; ++q)
            l[q] = make_float4(v[4 * q + 0], v[4 * q + 1], v[4 * q + 2], v[4 * q + 3]);
    }
    __syncthreads();

    // ---- Round 2: fixed (a,c), FWHT over digit b (h=16..128) ----
    {
        const int a = t >> 4, c = t & 15;
        const int base = a * 256 + c;
        const int xb = (a & 1) << 4;
#pragma unroll
        for (int b = 0; b < 16; ++b)
            v[b] = lds[(base + b * 16) ^ xb];
        fwht16(v);
#pragma unroll
        for (int b = 0; b < 16; ++b)
            lds[(base + b * 16) ^ xb] = v[b];
    }
    __syncthreads();

    // ---- Round 3: fixed (b,c)=t, FWHT over digit a (h=256..2048) ----
    {
#pragma unroll
        for (int a = 0; a < 16; ++a)
            v[a] = lds[(a * 256 + t) ^ ((a & 1) << 4)];
        fwht16(v);
#pragma unroll
        for (int a = 0; a < 16; ++a)
            lds[(a * 256 + t) ^ ((a & 1) << 4)] = v[a];
    }
    __syncthreads();

    // ---- Permutation gather + gauss_d; doubles as round 1 of 2nd FWHT ----
    {
        const int4* pv = (const int4*)(perm + t * 16);
        const float4* gv = (const float4*)(gauss_d + t * 16);
        int pidx[16];
        float g[16];
#pragma unroll
        for (int q = 0; q < 4; ++q) {
            int4 pp = pv[q];
            float4 gg = gv[q];
            pidx[4 * q + 0] = pp.x; pidx[4 * q + 1] = pp.y;
            pidx[4 * q + 2] = pp.z; pidx[4 * q + 3] = pp.w;
            g[4 * q + 0] = gg.x; g[4 * q + 1] = gg.y;
            g[4 * q + 2] = gg.z; g[4 * q + 3] = gg.w;
        }
#pragma unroll
        for (int k = 0; k < 16; ++k) {
            int pi = pidx[k];
            v[k] = lds[swz(pi)] * g[k];
        }
    }
    fwht16(v);          // digit c of j (register-only; overlaps barrier wait)
    __syncthreads();    // all gather reads done before overwrite
    {
        int g = t ^ ((t >> 4) & 1);
        float4* l = (float4*)(lds + g * 16);
#pragma unroll
        for (int q = 0; q < 4; ++q)
            l[q] = make_float4(v[4 * q + 0], v[4 * q + 1], v[4 * q + 2], v[4 * q + 3]);
    }
    __syncthreads();

    // ---- Round 2 of 2nd FWHT ----
    {
        const int a = t >> 4, c = t & 15;
        const int base = a * 256 + c;
        const int xb = (a & 1) << 4;
#pragma unroll
        for (int b = 0; b < 16; ++b)
            v[b] = lds[(base + b * 16) ^ xb];
        fwht16(v);
#pragma unroll
        for (int b = 0; b < 16; ++b)
            lds[(base + b * 16) ^ xb] = v[b];
    }
    __syncthreads();

    // ---- Round 3 of 2nd FWHT, fused * d2 * SCALE, direct global store ----
    {
#pragma unroll
        for (int a = 0; a < 16; ++a)
            v[a] = lds[(a * 256 + t) ^ ((a & 1) << 4)];
        fwht16(v);
        // element index for digit-a round is i = a*256 + t: per-a wave store
        // is 64 contiguous floats (256 B) — coalesced.
#pragma unroll
        for (int a = 0; a < 16; ++a) {
            int i = a * 256 + t;
            orow[i] = v[a] * d2[i] * FF_SCALE;
        }
    }
}

extern "C" void kernel_launch(void* const* d_in, const int* in_sizes, int n_in,
                              void* d_out, int out_size, void* d_ws, size_t ws_size,
                              hipStream_t stream) {
    const float* x       = (const float*)d_in[0];
    const float* d1      = (const float*)d_in[1];
    const float* d2      = (const float*)d_in[2];
    const float* gauss_d = (const float*)d_in[3];
    const int*   perm    = (const int*)d_in[4];
    float* out = (float*)d_out;

    const int batch = in_sizes[0] / DIM;  // 8192
    fastfood_kernel<<<batch, 256, 0, stream>>>(x, d1, d2, gauss_d, perm, out);
}